// Round 4
// baseline (372.450 us; speedup 1.0000x reference)
//
#include <hip/hip_runtime.h>
#include <stdint.h>

#define D 256
#define KCODES 1024
#define NROWS 65536

using short8 = __attribute__((ext_vector_type(8))) short;
using f32x4  = __attribute__((ext_vector_type(4))) float;

__device__ __forceinline__ float rne_f(float x) { return __builtin_rintf(x); }
__device__ __forceinline__ short f2bf(float x) { return (short)(__float_as_uint(x) >> 16); }

__device__ __forceinline__ void gl_lds16(const void* g, void* l) {
  __builtin_amdgcn_global_load_lds(
      (const __attribute__((address_space(1))) void*)g,
      (__attribute__((address_space(3))) void*)l, 16, 0, 0);
}

// ---------- numpy-exact pairwise sum of squares over 256 elements ----------
__device__ __forceinline__ float np_block128_sumsq(const float* __restrict__ q) {
  float r[8], v[8];
  *(float4*)(v) = *(const float4*)(q);
  *(float4*)(v + 4) = *(const float4*)(q + 4);
#pragma unroll
  for (int j = 0; j < 8; ++j) r[j] = __fmul_rn(v[j], v[j]);
  for (int i = 8; i < 128; i += 8) {
    *(float4*)(v) = *(const float4*)(q + i);
    *(float4*)(v + 4) = *(const float4*)(q + i + 4);
#pragma unroll
    for (int j = 0; j < 8; ++j) r[j] = __fadd_rn(r[j], __fmul_rn(v[j], v[j]));
  }
  float t01 = __fadd_rn(r[0], r[1]);
  float t23 = __fadd_rn(r[2], r[3]);
  float t45 = __fadd_rn(r[4], r[5]);
  float t67 = __fadd_rn(r[6], r[7]);
  return __fadd_rn(__fadd_rn(t01, t23), __fadd_rn(t45, t67));
}
__device__ __forceinline__ float np_sumsq256(const float* __restrict__ q) {
  return __fadd_rn(np_block128_sumsq(q), np_block128_sumsq(q + 128));
}

// prep1: srow[65536] and c2[1024], numpy-exact
__global__ void prep_sums(const float* __restrict__ z, const float* __restrict__ cb,
                          float* __restrict__ c2, float* __restrict__ srow) {
  int r = blockIdx.x * blockDim.x + threadIdx.x;
  if (r < NROWS) srow[r] = np_sumsq256(z + (size_t)r * D);
  else if (r < NROWS + KCODES) c2[r - NROWS] = np_sumsq256(cb + (size_t)(r - NROWS) * D);
}

// prep2: codebook -> 4 bf16 digit planes, k-major tile layout so the main
// kernel's wave-level ds_read is a contiguous 1024B block (zero bank conflicts):
// plane j, code-tile nt (32 codes): 16KB tile laid out as
//   [f(0..7)][c16(0..1)][kgrp(0..3)][code(0..15)][8 bf16]
// where element k-range of a 16B chunk = f*32 + kgrp*8 .. +8.
__global__ void prep_cbdig(const float* __restrict__ cb, short* __restrict__ cbd) {
  int id = blockIdx.x * blockDim.x + threadIdx.x;  // 32768 threads
  int n = id >> 5, k8 = id & 31;
  const float* src = cb + (size_t)n * D + k8 * 8;
  float v[8];
  *(float4*)(v) = *(const float4*)(src);
  *(float4*)(v + 4) = *(const float4*)(src + 4);
  short8 dig[4];
#pragma unroll
  for (int e = 0; e < 8; ++e) {
    float t = v[e] * 65536.0f;     // S_b: |c|*2^16 <= 64, digit |.|<=128
    float d0 = rne_f(t); t = __fmul_rn(__fsub_rn(t, d0), 256.0f);
    float d1 = rne_f(t); t = __fmul_rn(__fsub_rn(t, d1), 256.0f);
    float d2 = rne_f(t); t = __fmul_rn(__fsub_rn(t, d2), 256.0f);
    float d3 = rne_f(t);
    dig[0][e] = f2bf(d0); dig[1][e] = f2bf(d1); dig[2][e] = f2bf(d2); dig[3][e] = f2bf(d3);
  }
  int nt = n >> 5, c = n & 31;
  int dst_byte = nt * 16384 + (k8 >> 2) * 2048 + (c >> 4) * 1024 + (k8 & 3) * 256 + (c & 15) * 16;
#pragma unroll
  for (int j = 0; j < 4; ++j)
    *(short8*)((char*)cbd + (size_t)j * (KCODES * 512) + dst_byte) = dig[j];
}

// ---------------- main MFMA kernel ----------------
#define BM 64
#define BN 32
#define NT (KCODES / BN)

#define MF(a, b, c) __builtin_amdgcn_mfma_f32_16x16x32_bf16((a), (b), (c), 0, 0, 0)

// NOTE: no min-waves-per-EU here. With (256,2) the backend budgeted 256 total
// regs and split arch/AGPR 128/128, spilling the 128-reg Adig set (WRITE_SIZE
// showed ~144MB of scratch). Unconstrained, demand is ~220 total <= 256, so we
// keep 2 waves/SIMD occupancy WITHOUT spill.
__global__ __launch_bounds__(256) void vq_mfma(
    const float* __restrict__ z, const float* __restrict__ cb,
    const float* __restrict__ c2g, const float* __restrict__ srowg,
    const short* __restrict__ cbd, float* __restrict__ out) {
  __shared__ alignas(16) short bbuf[2][BN * D];  // 2 x 16 KB double-buffered B plane
  __shared__ float c2s[KCODES];
  __shared__ int bidx_s[BM];

  const int tid = threadIdx.x;
  const int lane = tid & 63;
  const int w = tid >> 6;  // wave 0..3, owns rows w*16..w*16+15
  const int r0 = blockIdx.x * BM;
  const int l15 = lane & 15, l4 = lane >> 4;

  c2s[tid] = c2g[tid];
  c2s[tid + 256] = c2g[tid + 256];
  c2s[tid + 512] = c2g[tid + 512];
  c2s[tid + 768] = c2g[tid + 768];

  float sr[4];
#pragma unroll
  for (int r = 0; r < 4; ++r) sr[r] = srowg[r0 + w * 16 + l4 * 4 + r];

  // ---- A digits: global -> regs -> 4 balanced radix-256 bf16 digit planes ----
  short8 Adig[4][8];
  {
    const float* zr = z + (size_t)(r0 + w * 16 + l15) * D + l4 * 8;
#pragma unroll
    for (int f = 0; f < 8; ++f) {
      float v[8];
      *(float4*)(v) = *(const float4*)(zr + f * 32);
      *(float4*)(v + 4) = *(const float4*)(zr + f * 32 + 4);
#pragma unroll
      for (int e = 0; e < 8; ++e) {
        float t = v[e] * 16.0f;  // S_a: |z|*16 <= ~90 < 128
        float d0 = rne_f(t); t = __fmul_rn(__fsub_rn(t, d0), 256.0f);
        float d1 = rne_f(t); t = __fmul_rn(__fsub_rn(t, d1), 256.0f);
        float d2 = rne_f(t); t = __fmul_rn(__fsub_rn(t, d2), 256.0f);
        float d3 = rne_f(t);
        Adig[0][f][e] = f2bf(d0); Adig[1][f][e] = f2bf(d1);
        Adig[2][f][e] = f2bf(d2); Adig[3][f][e] = f2bf(d3);
      }
    }
  }

  const char* cbd_b = (const char*)cbd;
#define STAGE(p) do { \
    int nt_ = (p) >> 2, j_ = (p) & 3; \
    const char* src_ = cbd_b + (size_t)j_ * (KCODES * 512) + (size_t)nt_ * 16384 + tid * 16; \
    char* dst_ = (char*)(&bbuf[(p) & 1][0]) + tid * 16; \
    gl_lds16(src_, dst_); gl_lds16(src_ + 4096, dst_ + 4096); \
    gl_lds16(src_ + 8192, dst_ + 8192); gl_lds16(src_ + 12288, dst_ + 12288); \
  } while (0)

  float bd[4]; int bi[4];
#pragma unroll
  for (int r = 0; r < 4; ++r) { bd[r] = 3.4e38f; bi[r] = 0x7fffffff; }

  f32x4 acc[4][2];

  STAGE(0);
  __syncthreads();

  for (int nt = 0; nt < NT; ++nt) {
#pragma unroll
    for (int s = 0; s < 4; ++s) {
      f32x4 zz = {0.f, 0.f, 0.f, 0.f};
      acc[s][0] = zz; acc[s][1] = zz;
    }
    const int pbase = nt * 4;
#pragma unroll
    for (int j = 0; j < 4; ++j) {
      const int p = pbase + j;
      if (p + 1 < NT * 4) STAGE(p + 1);  // issue next plane into other buffer
      const char* buf = (const char*)&bbuf[p & 1][0];
#pragma unroll
      for (int f = 0; f < 8; ++f) {
        // contiguous 1024B per wave per read: zero bank conflicts
        short8 B0 = *(const short8*)(buf + f * 2048 + lane * 16);
        short8 B1 = *(const short8*)(buf + f * 2048 + 1024 + lane * 16);
        acc[j + 0][0] = MF(Adig[0][f], B0, acc[j + 0][0]);
        acc[j + 0][1] = MF(Adig[0][f], B1, acc[j + 0][1]);
        if (j < 3) { acc[j + 1][0] = MF(Adig[1][f], B0, acc[j + 1][0]);
                     acc[j + 1][1] = MF(Adig[1][f], B1, acc[j + 1][1]); }
        if (j < 2) { acc[j + 2][0] = MF(Adig[2][f], B0, acc[j + 2][0]);
                     acc[j + 2][1] = MF(Adig[2][f], B1, acc[j + 2][1]); }
        if (j < 1) { acc[j + 3][0] = MF(Adig[3][f], B0, acc[j + 3][0]);
                     acc[j + 3][1] = MF(Adig[3][f], B1, acc[j + 3][1]); }
      }
      __syncthreads();  // drains stage(p+1) loads AND all readers of bbuf[p&1]
    }
    // finalize this code-tile: exact fp64 Horner recombination of integer group sums
#pragma unroll
    for (int n = 0; n < 2; ++n) {
#pragma unroll
      for (int r = 0; r < 4; ++r) {
        double md = fma(fma(fma((double)acc[3][n][r], 0x1p-8,
                                (double)acc[2][n][r]), 0x1p-8,
                            (double)acc[1][n][r]), 0x1p-8,
                        (double)acc[0][n][r]) * 0x1p-20;  // every step exact in fp64
        float mf = (float)md;
        int kc = nt * BN + n * 16 + l15;
        float dist = __fsub_rn(__fadd_rn(sr[r], c2s[kc]), __fmul_rn(2.0f, mf));
        if (dist < bd[r]) { bd[r] = dist; bi[r] = kc; }  // ascending kc => first-min
      }
    }
  }

  // per-row argmin across the 16 lanes of each row group (np tie-break: lowest idx)
#pragma unroll
  for (int r = 0; r < 4; ++r) {
#pragma unroll
    for (int m = 1; m < 16; m <<= 1) {
      float od = __shfl_xor(bd[r], m);
      int oi = __shfl_xor(bi[r], m);
      if (od < bd[r] || (od == bd[r] && oi < bi[r])) { bd[r] = od; bi[r] = oi; }
    }
    if (l15 == 0) bidx_s[w * 16 + l4 * 4 + r] = bi[r];
  }
  __syncthreads();

  // epilogue: gather codes, z_q = fl(z + fl(c - z)), z_q_bar = c
  {
    const int row_l = tid >> 2, seg = tid & 3;
    const int grow = r0 + row_l;
    const int kb = bidx_s[row_l];
    const float* crow = cb + (size_t)kb * D;
    const float* zrow = z + (size_t)grow * D;
    float* o0 = out + (size_t)grow * D;
    float* o1 = out + (size_t)NROWS * D + (size_t)grow * D;
#pragma unroll
    for (int ii = 0; ii < 16; ++ii) {
      int q = seg * 16 + ii;
      float4 c4 = *(const float4*)(crow + q * 4);
      float4 z4 = *(const float4*)(zrow + q * 4);
      float4 o;
      o.x = __fadd_rn(z4.x, __fsub_rn(c4.x, z4.x));
      o.y = __fadd_rn(z4.y, __fsub_rn(c4.y, z4.y));
      o.z = __fadd_rn(z4.z, __fsub_rn(c4.z, z4.z));
      o.w = __fadd_rn(z4.w, __fsub_rn(c4.w, z4.w));
      *(float4*)(o0 + q * 4) = o;
      *(float4*)(o1 + q * 4) = c4;
    }
  }
}

// ---------------- fallback (exact fp64 dot) if ws is too small ----------------
__global__ void c2_kernel_fb(const float* __restrict__ cb, float* __restrict__ c2) {
  int k = blockIdx.x * blockDim.x + threadIdx.x;
  if (k < KCODES) c2[k] = np_sumsq256(cb + (size_t)k * D);
}

__global__ __launch_bounds__(256) void vq_fallback(const float* __restrict__ z,
                                                   const float* __restrict__ cb,
                                                   const float* __restrict__ c2,
                                                   float* __restrict__ out) {
  __shared__ float zs[64][260];
  __shared__ float cs[64][260];
  __shared__ float srow[64];
  __shared__ int bidx[64];
  const int tid = threadIdx.x;
  const int tx = tid & 15, ty = tid >> 4;
  const int r0 = blockIdx.x * 64;
#pragma unroll
  for (int it = 0; it < 16; ++it) {
    int g = tid + it * 256, row = g >> 6, f4 = g & 63;
    *(float4*)(&zs[row][f4 * 4]) = *(const float4*)(z + (size_t)(r0 + row) * D + f4 * 4);
  }
  __syncthreads();
  if (tid < 64) srow[tid] = np_sumsq256(&zs[tid][0]);
  float bd[4]; int bi[4];
#pragma unroll
  for (int j = 0; j < 4; ++j) { bd[j] = 3.4e38f; bi[j] = 0x7fffffff; }
  for (int t = 0; t < KCODES / 64; ++t) {
    __syncthreads();
#pragma unroll
    for (int it = 0; it < 16; ++it) {
      int g = tid + it * 256, row = g >> 6, f4 = g & 63;
      *(float4*)(&cs[row][f4 * 4]) = *(const float4*)(cb + (size_t)(t * 64 + row) * D + f4 * 4);
    }
    __syncthreads();
    double acc[4][4];
#pragma unroll
    for (int j = 0; j < 4; ++j)
#pragma unroll
      for (int i = 0; i < 4; ++i) acc[j][i] = 0.0;
#pragma unroll 2
    for (int d = 0; d < D; d += 4) {
      float4 a[4], b[4];
#pragma unroll
      for (int j = 0; j < 4; ++j) a[j] = *(const float4*)(&zs[ty + 16 * j][d]);
#pragma unroll
      for (int i = 0; i < 4; ++i) b[i] = *(const float4*)(&cs[tx + 16 * i][d]);
#pragma unroll
      for (int j = 0; j < 4; ++j)
#pragma unroll
        for (int i = 0; i < 4; ++i) {
          acc[j][i] += (double)a[j].x * (double)b[i].x;
          acc[j][i] += (double)a[j].y * (double)b[i].y;
          acc[j][i] += (double)a[j].z * (double)b[i].z;
          acc[j][i] += (double)a[j].w * (double)b[i].w;
        }
    }
#pragma unroll
    for (int j = 0; j < 4; ++j) {
      const float s = srow[ty + 16 * j];
#pragma unroll
      for (int i = 0; i < 4; ++i) {
        const int k = t * 64 + tx + 16 * i;
        const float m = (float)acc[j][i];
        const float dist = __fsub_rn(__fadd_rn(s, c2[k]), __fmul_rn(2.0f, m));
        if (dist < bd[j]) { bd[j] = dist; bi[j] = k; }
      }
    }
  }
  __syncthreads();
  float* red_d = &cs[0][0];
  int* red_i = (int*)&cs[20][0];
#pragma unroll
  for (int j = 0; j < 4; ++j) {
    red_d[(ty + 16 * j) * 16 + tx] = bd[j];
    red_i[(ty + 16 * j) * 16 + tx] = bi[j];
  }
  __syncthreads();
  if (tid < 64) {
    float best = red_d[tid * 16 + 0];
    int bsti = red_i[tid * 16 + 0];
    for (int x = 1; x < 16; ++x) {
      float d2 = red_d[tid * 16 + x]; int i2 = red_i[tid * 16 + x];
      if (d2 < best || (d2 == best && i2 < bsti)) { best = d2; bsti = i2; }
    }
    bidx[tid] = bsti;
  }
  __syncthreads();
  const int wid = tid >> 6, lane = tid & 63;
  float* out0 = out;
  float* out1 = out + (size_t)NROWS * D;
  for (int r = wid; r < 64; r += 4) {
    const int gr = r0 + r;
    const int kb = bidx[r];
    float4 c4 = *(const float4*)(cb + (size_t)kb * D + lane * 4);
    float4 z4 = *(const float4*)(&zs[r][lane * 4]);
    float4 q;
    q.x = __fadd_rn(z4.x, __fsub_rn(c4.x, z4.x));
    q.y = __fadd_rn(z4.y, __fsub_rn(c4.y, z4.y));
    q.z = __fadd_rn(z4.z, __fsub_rn(c4.z, z4.z));
    q.w = __fadd_rn(z4.w, __fsub_rn(c4.w, z4.w));
    *(float4*)(out0 + (size_t)gr * D + lane * 4) = q;
    *(float4*)(out1 + (size_t)gr * D + lane * 4) = c4;
  }
}

extern "C" void kernel_launch(void* const* d_in, const int* in_sizes, int n_in,
                              void* d_out, int out_size, void* d_ws, size_t ws_size,
                              hipStream_t stream) {
  const float* z = (const float*)d_in[0];
  const float* cb = (const float*)d_in[1];
  float* out = (float*)d_out;

  const size_t c2_off = 0;                 // 4 KB
  const size_t srow_off = 4096;            // 256 KB
  const size_t cbd_off = 4096 + 262144;    // 2 MB digit planes
  const size_t need = cbd_off + (size_t)4 * KCODES * 512;

  if (ws_size < need) {  // safety fallback: exact fp64 path
    float* c2 = (float*)d_ws;
    c2_kernel_fb<<<KCODES / 256, 256, 0, stream>>>(cb, c2);
    vq_fallback<<<NROWS / 64, 256, 0, stream>>>(z, cb, c2, out);
    return;
  }

  float* c2 = (float*)((char*)d_ws + c2_off);
  float* srow = (float*)((char*)d_ws + srow_off);
  short* cbd = (short*)((char*)d_ws + cbd_off);

  prep_sums<<<(NROWS + KCODES) / 256, 256, 0, stream>>>(z, cb, c2, srow);
  prep_cbdig<<<(KCODES * 32) / 256, 256, 0, stream>>>(cb, cbd);
  vq_mfma<<<NROWS / BM, 256, 0, stream>>>(z, cb, c2, srow, cbd, out);
}

// Round 5
// 294.788 us; speedup vs baseline: 1.2635x; 1.2635x over previous
//
#include <hip/hip_runtime.h>
#include <stdint.h>

#define D 256
#define KCODES 1024
#define NROWS 65536

using int4v = __attribute__((ext_vector_type(4))) int;

__device__ __forceinline__ float rne_f(float x) { return __builtin_rintf(x); }

__device__ __forceinline__ void gl_lds16(const void* g, void* l) {
  __builtin_amdgcn_global_load_lds(
      (const __attribute__((address_space(1))) void*)g,
      (__attribute__((address_space(3))) void*)l, 16, 0, 0);
}

// 4 balanced radix-256 digits of t (|t| <= ~92), each in [-128,127] after an
// exact borrow re-encode of the +128 boundary. Represented value identical to
// the rounds-2..4 bf16 digit chain (same rne sequence) => bit-identical m.
__device__ __forceinline__ void dig4(float t, int* d) {
  float f0 = rne_f(t);  float t1 = __fmul_rn(__fsub_rn(t, f0), 256.0f);
  float f1 = rne_f(t1); float t2 = __fmul_rn(__fsub_rn(t1, f1), 256.0f);
  float f2 = rne_f(t2); float t3 = __fmul_rn(__fsub_rn(t2, f2), 256.0f);
  float f3 = rne_f(t3);
  int d0 = (int)f0, d1 = (int)f1, d2 = (int)f2, d3 = (int)f3;
  if (d3 == 128) { d3 = -128; ++d2; }
  if (d2 == 128) { d2 = -128; ++d1; }
  if (d1 == 128) { d1 = -128; ++d0; }
  d[0] = d0; d[1] = d1; d[2] = d2; d[3] = d3;
}

// ---------- numpy-exact pairwise sum of squares over 256 elements ----------
__device__ __forceinline__ float np_block128_sumsq(const float* __restrict__ q) {
  float r[8], v[8];
  *(float4*)(v) = *(const float4*)(q);
  *(float4*)(v + 4) = *(const float4*)(q + 4);
#pragma unroll
  for (int j = 0; j < 8; ++j) r[j] = __fmul_rn(v[j], v[j]);
  for (int i = 8; i < 128; i += 8) {
    *(float4*)(v) = *(const float4*)(q + i);
    *(float4*)(v + 4) = *(const float4*)(q + i + 4);
#pragma unroll
    for (int j = 0; j < 8; ++j) r[j] = __fadd_rn(r[j], __fmul_rn(v[j], v[j]));
  }
  float t01 = __fadd_rn(r[0], r[1]);
  float t23 = __fadd_rn(r[2], r[3]);
  float t45 = __fadd_rn(r[4], r[5]);
  float t67 = __fadd_rn(r[6], r[7]);
  return __fadd_rn(__fadd_rn(t01, t23), __fadd_rn(t45, t67));
}
__device__ __forceinline__ float np_sumsq256(const float* __restrict__ q) {
  return __fadd_rn(np_block128_sumsq(q), np_block128_sumsq(q + 128));
}

// prep1: srow[65536] and c2[1024], numpy-exact
__global__ void prep_sums(const float* __restrict__ z, const float* __restrict__ cb,
                          float* __restrict__ c2, float* __restrict__ srow) {
  int r = blockIdx.x * blockDim.x + threadIdx.x;
  if (r < NROWS) srow[r] = np_sumsq256(z + (size_t)r * D);
  else if (r < NROWS + KCODES) c2[r - NROWS] = np_sumsq256(cb + (size_t)(r - NROWS) * D);
}

// prep2: codebook -> 4 int8 digit planes, k-major tile layout: plane j,
// code-tile nt (32 codes) is an 8KB tile [f(0..3)][c16(0..1)][kgrp(0..3)]
// [code(0..15)][16 i8], where the 16B chunk covers k = f*64 + kgrp*16 .. +16.
// Wave-level ds_read in the main kernel = contiguous 1024B => 0 bank conflicts.
__global__ void prep_cbdig(const float* __restrict__ cb, char* __restrict__ cbd) {
  int id = blockIdx.x * blockDim.x + threadIdx.x;  // 16384 threads
  int n = id >> 4, kc = id & 15;
  int f = kc >> 2, kg = kc & 3, nt = n >> 5, c = n & 31;
  const float* src = cb + (size_t)n * D + kc * 16;
  float v[16];
  *(float4*)(v) = *(const float4*)(src);
  *(float4*)(v + 4) = *(const float4*)(src + 4);
  *(float4*)(v + 8) = *(const float4*)(src + 8);
  *(float4*)(v + 12) = *(const float4*)(src + 12);
  int dg[16][4];
#pragma unroll
  for (int e = 0; e < 16; ++e) dig4(v[e] * 65536.0f, dg[e]);  // |c*2^16| <= 64
  size_t base = (size_t)nt * 8192 + f * 2048 + (c >> 4) * 1024 + kg * 256 + (c & 15) * 16;
#pragma unroll
  for (int p = 0; p < 4; ++p) {
    int4v wv;
#pragma unroll
    for (int wi = 0; wi < 4; ++wi)
      wv[wi] = (dg[wi * 4][p] & 255) | ((dg[wi * 4 + 1][p] & 255) << 8) |
               ((dg[wi * 4 + 2][p] & 255) << 16) | (dg[wi * 4 + 3][p] << 24);
    *(int4v*)(cbd + (size_t)p * (KCODES * 256) + base) = wv;
  }
}

// ---------------- main MFMA kernel (int8, exact integer accumulation) ----------------
#define BM 64
#define BN 32
#define NT (KCODES / BN)

#define MFI(a, b, c) __builtin_amdgcn_mfma_i32_16x16x64_i8((a), (b), (c), 0, 0, 0)

__global__ __launch_bounds__(256, 1) void vq_mfma(
    const float* __restrict__ z, const float* __restrict__ cb,
    const float* __restrict__ c2g, const float* __restrict__ srowg,
    const char* __restrict__ cbd, float* __restrict__ out) {
  __shared__ alignas(16) char bbuf[2][8192];  // double-buffered 8KB B plane tile
  __shared__ float c2s[KCODES];
  __shared__ int bidx_s[BM];

  const int tid = threadIdx.x;
  const int lane = tid & 63;
  const int w = tid >> 6;  // wave 0..3, owns rows w*16..w*16+15
  const int r0 = blockIdx.x * BM;
  const int l15 = lane & 15, l4 = lane >> 4;

  c2s[tid] = c2g[tid];
  c2s[tid + 256] = c2g[tid + 256];
  c2s[tid + 512] = c2g[tid + 512];
  c2s[tid + 768] = c2g[tid + 768];

  float sr[4];
#pragma unroll
  for (int r = 0; r < 4; ++r) sr[r] = srowg[r0 + w * 16 + l4 * 4 + r];

  // ---- A digits: global -> regs -> 4 radix-256 int8 digit planes (64 VGPR) ----
  // lane holds row = w*16+l15; frag f covers k = f*64 + l4*16 .. +16
  int4v Adig[4][4];
  {
    const float* zr = z + (size_t)(r0 + w * 16 + l15) * D + l4 * 16;
#pragma unroll
    for (int f = 0; f < 4; ++f) {
      float v[16];
      *(float4*)(v) = *(const float4*)(zr + f * 64);
      *(float4*)(v + 4) = *(const float4*)(zr + f * 64 + 4);
      *(float4*)(v + 8) = *(const float4*)(zr + f * 64 + 8);
      *(float4*)(v + 12) = *(const float4*)(zr + f * 64 + 12);
      int dg[16][4];
#pragma unroll
      for (int e = 0; e < 16; ++e) dig4(v[e] * 16.0f, dg[e]);  // |z*16| <= ~92
#pragma unroll
      for (int p = 0; p < 4; ++p) {
        int4v wv;
#pragma unroll
        for (int wi = 0; wi < 4; ++wi)
          wv[wi] = (dg[wi * 4][p] & 255) | ((dg[wi * 4 + 1][p] & 255) << 8) |
                   ((dg[wi * 4 + 2][p] & 255) << 16) | (dg[wi * 4 + 3][p] << 24);
        Adig[p][f] = wv;
      }
    }
  }

  const char* cbd_b = cbd;
#define STAGE(p) do { \
    int nt_ = (p) >> 2, j_ = (p) & 3; \
    const char* src_ = cbd_b + (size_t)j_ * (KCODES * 256) + (size_t)nt_ * 8192 + tid * 16; \
    char* dst_ = &bbuf[(p) & 1][0] + tid * 16; \
    gl_lds16(src_, dst_); gl_lds16(src_ + 4096, dst_ + 4096); \
  } while (0)

  float bd[4]; int bi[4];
#pragma unroll
  for (int r = 0; r < 4; ++r) { bd[r] = 3.4e38f; bi[r] = 0x7fffffff; }

  int4v acc[4][2];

  STAGE(0);
  __syncthreads();

  for (int nt = 0; nt < NT; ++nt) {
#pragma unroll
    for (int s = 0; s < 4; ++s) {
      int4v zz = {0, 0, 0, 0};
      acc[s][0] = zz; acc[s][1] = zz;
    }
    const int pbase = nt * 4;
#pragma unroll
    for (int j = 0; j < 4; ++j) {
      const int p = pbase + j;
      if (p + 1 < NT * 4) STAGE(p + 1);  // issue next plane into other buffer
      const char* buf = &bbuf[p & 1][0];
#pragma unroll
      for (int f = 0; f < 4; ++f) {
        // contiguous 1024B per wave per read: zero bank conflicts
        int4v B0 = *(const int4v*)(buf + f * 2048 + lane * 16);
        int4v B1 = *(const int4v*)(buf + f * 2048 + 1024 + lane * 16);
        acc[j + 0][0] = MFI(Adig[0][f], B0, acc[j + 0][0]);
        acc[j + 0][1] = MFI(Adig[0][f], B1, acc[j + 0][1]);
        if (j < 3) { acc[j + 1][0] = MFI(Adig[1][f], B0, acc[j + 1][0]);
                     acc[j + 1][1] = MFI(Adig[1][f], B1, acc[j + 1][1]); }
        if (j < 2) { acc[j + 2][0] = MFI(Adig[2][f], B0, acc[j + 2][0]);
                     acc[j + 2][1] = MFI(Adig[2][f], B1, acc[j + 2][1]); }
        if (j < 1) { acc[j + 3][0] = MFI(Adig[3][f], B0, acc[j + 3][0]);
                     acc[j + 3][1] = MFI(Adig[3][f], B1, acc[j + 3][1]); }
      }
      __syncthreads();  // drains stage(p+1) loads AND all readers of bbuf[p&1]
    }
    // finalize: exact int64 recombination of integer group sums, one fp32 rounding
#pragma unroll
    for (int n = 0; n < 2; ++n) {
#pragma unroll
      for (int r = 0; r < 4; ++r) {
        long M = (long)acc[0][n][r];
        M = (M << 8) + acc[1][n][r];
        M = (M << 8) + acc[2][n][r];
        M = (M << 8) + acc[3][n][r];              // = sum_s acc_s * 256^(3-s), exact
        float mf = (float)((double)M * 0x1p-44);  // m rounded once (bit-identical to r2-r4)
        int kc = nt * BN + n * 16 + l15;
        float dist = __fsub_rn(__fadd_rn(sr[r], c2s[kc]), __fmul_rn(2.0f, mf));
        if (dist < bd[r]) { bd[r] = dist; bi[r] = kc; }  // ascending kc => first-min
      }
    }
  }

  // per-row argmin across the 16 lanes of each row group (np tie-break: lowest idx)
#pragma unroll
  for (int r = 0; r < 4; ++r) {
#pragma unroll
    for (int m = 1; m < 16; m <<= 1) {
      float od = __shfl_xor(bd[r], m);
      int oi = __shfl_xor(bi[r], m);
      if (od < bd[r] || (od == bd[r] && oi < bi[r])) { bd[r] = od; bi[r] = oi; }
    }
    if (l15 == 0) bidx_s[w * 16 + l4 * 4 + r] = bi[r];
  }
  __syncthreads();

  // epilogue: gather codes, z_q = fl(z + fl(c - z)), z_q_bar = c
  {
    const int row_l = tid >> 2, seg = tid & 3;
    const int grow = r0 + row_l;
    const int kb = bidx_s[row_l];
    const float* crow = cb + (size_t)kb * D;
    const float* zrow = z + (size_t)grow * D;
    float* o0 = out + (size_t)grow * D;
    float* o1 = out + (size_t)NROWS * D + (size_t)grow * D;
#pragma unroll
    for (int ii = 0; ii < 16; ++ii) {
      int q = seg * 16 + ii;
      float4 c4 = *(const float4*)(crow + q * 4);
      float4 z4 = *(const float4*)(zrow + q * 4);
      float4 o;
      o.x = __fadd_rn(z4.x, __fsub_rn(c4.x, z4.x));
      o.y = __fadd_rn(z4.y, __fsub_rn(c4.y, z4.y));
      o.z = __fadd_rn(z4.z, __fsub_rn(c4.z, z4.z));
      o.w = __fadd_rn(z4.w, __fsub_rn(c4.w, z4.w));
      *(float4*)(o0 + q * 4) = o;
      *(float4*)(o1 + q * 4) = c4;
    }
  }
}

// ---------------- fallback (exact fp64 dot) if ws is too small ----------------
__global__ void c2_kernel_fb(const float* __restrict__ cb, float* __restrict__ c2) {
  int k = blockIdx.x * blockDim.x + threadIdx.x;
  if (k < KCODES) c2[k] = np_sumsq256(cb + (size_t)k * D);
}

__global__ __launch_bounds__(256) void vq_fallback(const float* __restrict__ z,
                                                   const float* __restrict__ cb,
                                                   const float* __restrict__ c2,
                                                   float* __restrict__ out) {
  __shared__ float zs[64][260];
  __shared__ float cs[64][260];
  __shared__ float srow[64];
  __shared__ int bidx[64];
  const int tid = threadIdx.x;
  const int tx = tid & 15, ty = tid >> 4;
  const int r0 = blockIdx.x * 64;
#pragma unroll
  for (int it = 0; it < 16; ++it) {
    int g = tid + it * 256, row = g >> 6, f4 = g & 63;
    *(float4*)(&zs[row][f4 * 4]) = *(const float4*)(z + (size_t)(r0 + row) * D + f4 * 4);
  }
  __syncthreads();
  if (tid < 64) srow[tid] = np_sumsq256(&zs[tid][0]);
  float bd[4]; int bi[4];
#pragma unroll
  for (int j = 0; j < 4; ++j) { bd[j] = 3.4e38f; bi[j] = 0x7fffffff; }
  for (int t = 0; t < KCODES / 64; ++t) {
    __syncthreads();
#pragma unroll
    for (int it = 0; it < 16; ++it) {
      int g = tid + it * 256, row = g >> 6, f4 = g & 63;
      *(float4*)(&cs[row][f4 * 4]) = *(const float4*)(cb + (size_t)(t * 64 + row) * D + f4 * 4);
    }
    __syncthreads();
    double acc[4][4];
#pragma unroll
    for (int j = 0; j < 4; ++j)
#pragma unroll
      for (int i = 0; i < 4; ++i) acc[j][i] = 0.0;
#pragma unroll 2
    for (int d = 0; d < D; d += 4) {
      float4 a[4], b[4];
#pragma unroll
      for (int j = 0; j < 4; ++j) a[j] = *(const float4*)(&zs[ty + 16 * j][d]);
#pragma unroll
      for (int i = 0; i < 4; ++i) b[i] = *(const float4*)(&cs[tx + 16 * i][d]);
#pragma unroll
      for (int j = 0; j < 4; ++j)
#pragma unroll
        for (int i = 0; i < 4; ++i) {
          acc[j][i] += (double)a[j].x * (double)b[i].x;
          acc[j][i] += (double)a[j].y * (double)b[i].y;
          acc[j][i] += (double)a[j].z * (double)b[i].z;
          acc[j][i] += (double)a[j].w * (double)b[i].w;
        }
    }
#pragma unroll
    for (int j = 0; j < 4; ++j) {
      const float s = srow[ty + 16 * j];
#pragma unroll
      for (int i = 0; i < 4; ++i) {
        const int k = t * 64 + tx + 16 * i;
        const float m = (float)acc[j][i];
        const float dist = __fsub_rn(__fadd_rn(s, c2[k]), __fmul_rn(2.0f, m));
        if (dist < bd[j]) { bd[j] = dist; bi[j] = k; }
      }
    }
  }
  __syncthreads();
  float* red_d = &cs[0][0];
  int* red_i = (int*)&cs[20][0];
#pragma unroll
  for (int j = 0; j < 4; ++j) {
    red_d[(ty + 16 * j) * 16 + tx] = bd[j];
    red_i[(ty + 16 * j) * 16 + tx] = bi[j];
  }
  __syncthreads();
  if (tid < 64) {
    float best = red_d[tid * 16 + 0];
    int bsti = red_i[tid * 16 + 0];
    for (int x = 1; x < 16; ++x) {
      float d2 = red_d[tid * 16 + x]; int i2 = red_i[tid * 16 + x];
      if (d2 < best || (d2 == best && i2 < bsti)) { best = d2; bsti = i2; }
    }
    bidx[tid] = bsti;
  }
  __syncthreads();
  const int wid = tid >> 6, lane = tid & 63;
  float* out0 = out;
  float* out1 = out + (size_t)NROWS * D;
  for (int r = wid; r < 64; r += 4) {
    const int gr = r0 + r;
    const int kb = bidx[r];
    float4 c4 = *(const float4*)(cb + (size_t)kb * D + lane * 4);
    float4 z4 = *(const float4*)(&zs[r][lane * 4]);
    float4 q;
    q.x = __fadd_rn(z4.x, __fsub_rn(c4.x, z4.x));
    q.y = __fadd_rn(z4.y, __fsub_rn(c4.y, z4.y));
    q.z = __fadd_rn(z4.z, __fsub_rn(c4.z, z4.z));
    q.w = __fadd_rn(z4.w, __fsub_rn(c4.w, z4.w));
    *(float4*)(out0 + (size_t)gr * D + lane * 4) = q;
    *(float4*)(out1 + (size_t)gr * D + lane * 4) = c4;
  }
}

extern "C" void kernel_launch(void* const* d_in, const int* in_sizes, int n_in,
                              void* d_out, int out_size, void* d_ws, size_t ws_size,
                              hipStream_t stream) {
  const float* z = (const float*)d_in[0];
  const float* cb = (const float*)d_in[1];
  float* out = (float*)d_out;

  const size_t c2_off = 0;                 // 4 KB
  const size_t srow_off = 4096;            // 256 KB
  const size_t cbd_off = 4096 + 262144;    // 1 MB int8 digit planes
  const size_t need = cbd_off + (size_t)4 * KCODES * 256;

  if (ws_size < need) {  // safety fallback: exact fp64 path
    float* c2 = (float*)d_ws;
    c2_kernel_fb<<<KCODES / 256, 256, 0, stream>>>(cb, c2);
    vq_fallback<<<NROWS / 64, 256, 0, stream>>>(z, cb, c2, out);
    return;
  }

  float* c2 = (float*)((char*)d_ws + c2_off);
  float* srow = (float*)((char*)d_ws + srow_off);
  char* cbd = (char*)d_ws + cbd_off;

  prep_sums<<<(NROWS + KCODES) / 256, 256, 0, stream>>>(z, cb, c2, srow);
  prep_cbdig<<<(KCODES * 16) / 256, 256, 0, stream>>>(cb, cbd);
  vq_mfma<<<NROWS / BM, 256, 0, stream>>>(z, cb, c2, srow, cbd, out);
}

// Round 6
// 214.742 us; speedup vs baseline: 1.7344x; 1.3728x over previous
//
#include <hip/hip_runtime.h>
#include <stdint.h>

#define D 256
#define KCODES 1024
#define NROWS 65536

using int4v = __attribute__((ext_vector_type(4))) int;

__device__ __forceinline__ float rne_f(float x) { return __builtin_rintf(x); }

__device__ __forceinline__ void gl_lds16(const void* g, void* l) {
  __builtin_amdgcn_global_load_lds(
      (const __attribute__((address_space(1))) void*)g,
      (__attribute__((address_space(3))) void*)l, 16, 0, 0);
}

// 4 balanced radix-256 digits of t (|t| <= ~92), each in [-128,127] after an
// exact borrow re-encode of the +128 boundary. Represented value identical to
// the rounds-2..5 digit chain => bit-identical m.
__device__ __forceinline__ void dig4(float t, int* d) {
  float f0 = rne_f(t);  float t1 = __fmul_rn(__fsub_rn(t, f0), 256.0f);
  float f1 = rne_f(t1); float t2 = __fmul_rn(__fsub_rn(t1, f1), 256.0f);
  float f2 = rne_f(t2); float t3 = __fmul_rn(__fsub_rn(t2, f2), 256.0f);
  float f3 = rne_f(t3);
  int d0 = (int)f0, d1 = (int)f1, d2 = (int)f2, d3 = (int)f3;
  if (d3 == 128) { d3 = -128; ++d2; }
  if (d2 == 128) { d2 = -128; ++d1; }
  if (d1 == 128) { d1 = -128; ++d0; }
  d[0] = d0; d[1] = d1; d[2] = d2; d[3] = d3;
}

// ---------- numpy-exact pairwise sum of squares over 256 elements ----------
__device__ __forceinline__ float np_block128_sumsq(const float* __restrict__ q) {
  float r[8], v[8];
  *(float4*)(v) = *(const float4*)(q);
  *(float4*)(v + 4) = *(const float4*)(q + 4);
#pragma unroll
  for (int j = 0; j < 8; ++j) r[j] = __fmul_rn(v[j], v[j]);
  for (int i = 8; i < 128; i += 8) {
    *(float4*)(v) = *(const float4*)(q + i);
    *(float4*)(v + 4) = *(const float4*)(q + i + 4);
#pragma unroll
    for (int j = 0; j < 8; ++j) r[j] = __fadd_rn(r[j], __fmul_rn(v[j], v[j]));
  }
  float t01 = __fadd_rn(r[0], r[1]);
  float t23 = __fadd_rn(r[2], r[3]);
  float t45 = __fadd_rn(r[4], r[5]);
  float t67 = __fadd_rn(r[6], r[7]);
  return __fadd_rn(__fadd_rn(t01, t23), __fadd_rn(t45, t67));
}
__device__ __forceinline__ float np_sumsq256(const float* __restrict__ q) {
  return __fadd_rn(np_block128_sumsq(q), np_block128_sumsq(q + 128));
}

// prep1: srow[65536] and c2[1024], numpy-exact
__global__ void prep_sums(const float* __restrict__ z, const float* __restrict__ cb,
                          float* __restrict__ c2, float* __restrict__ srow) {
  int r = blockIdx.x * blockDim.x + threadIdx.x;
  if (r < NROWS) srow[r] = np_sumsq256(z + (size_t)r * D);
  else if (r < NROWS + KCODES) c2[r - NROWS] = np_sumsq256(cb + (size_t)(r - NROWS) * D);
}

// prep2: codebook -> 4 int8 digit planes, k-major tile layout: plane j,
// code-tile nt (32 codes) is an 8KB tile [f(0..3)][c16(0..1)][kgrp(0..3)]
// [code(0..15)][16 i8], where the 16B chunk covers k = f*64 + kgrp*16 .. +16.
// Wave-level ds_read in the main kernel = contiguous 1024B => 0 bank conflicts.
__global__ void prep_cbdig(const float* __restrict__ cb, char* __restrict__ cbd) {
  int id = blockIdx.x * blockDim.x + threadIdx.x;  // 16384 threads
  int n = id >> 4, kc = id & 15;
  int f = kc >> 2, kg = kc & 3, nt = n >> 5, c = n & 31;
  const float* src = cb + (size_t)n * D + kc * 16;
  float v[16];
  *(float4*)(v) = *(const float4*)(src);
  *(float4*)(v + 4) = *(const float4*)(src + 4);
  *(float4*)(v + 8) = *(const float4*)(src + 8);
  *(float4*)(v + 12) = *(const float4*)(src + 12);
  int dg[16][4];
#pragma unroll
  for (int e = 0; e < 16; ++e) dig4(v[e] * 65536.0f, dg[e]);  // |c*2^16| <= 64
  size_t base = (size_t)nt * 8192 + f * 2048 + (c >> 4) * 1024 + kg * 256 + (c & 15) * 16;
#pragma unroll
  for (int p = 0; p < 4; ++p) {
    int4v wv;
#pragma unroll
    for (int wi = 0; wi < 4; ++wi)
      wv[wi] = (dg[wi * 4][p] & 255) | ((dg[wi * 4 + 1][p] & 255) << 8) |
               ((dg[wi * 4 + 2][p] & 255) << 16) | (dg[wi * 4 + 3][p] << 24);
    *(int4v*)(cbd + (size_t)p * (KCODES * 256) + base) = wv;
  }
}

// ---------------- main MFMA kernel (int8, exact integer accumulation) ----------------
#define BM 64
#define BN 32
#define NT (KCODES / BN)

#define MFI(a, b, c) __builtin_amdgcn_mfma_i32_16x16x64_i8((a), (b), (c), 0, 0, 0)

__global__ __launch_bounds__(256, 1) void vq_mfma(
    const float* __restrict__ z, const float* __restrict__ cb,
    const float* __restrict__ c2g, const float* __restrict__ srowg,
    const char* __restrict__ cbd, float* __restrict__ out) {
  // double-buffered: per buffer all 4 planes of one 32-code tile (4 x 8KB)
  __shared__ alignas(16) char bbuf[2][32768];
  __shared__ float c2s[KCODES];
  __shared__ int bidx_s[BM];

  const int tid = threadIdx.x;
  const int lane = tid & 63;
  const int w = tid >> 6;  // wave 0..3, owns rows w*16..w*16+15
  const int r0 = blockIdx.x * BM;
  const int l15 = lane & 15, l4 = lane >> 4;

  c2s[tid] = c2g[tid];
  c2s[tid + 256] = c2g[tid + 256];
  c2s[tid + 512] = c2g[tid + 512];
  c2s[tid + 768] = c2g[tid + 768];

  float sr[4];
#pragma unroll
  for (int r = 0; r < 4; ++r) sr[r] = srowg[r0 + w * 16 + l4 * 4 + r];

  // ---- A digits: global -> regs -> 4 radix-256 int8 digit planes (64 VGPR) ----
  // lane holds row = w*16+l15; frag f covers k = f*64 + l4*16 .. +16
  int4v Adig[4][4];
  {
    const float* zr = z + (size_t)(r0 + w * 16 + l15) * D + l4 * 16;
#pragma unroll
    for (int f = 0; f < 4; ++f) {
      float v[16];
      *(float4*)(v) = *(const float4*)(zr + f * 64);
      *(float4*)(v + 4) = *(const float4*)(zr + f * 64 + 4);
      *(float4*)(v + 8) = *(const float4*)(zr + f * 64 + 8);
      *(float4*)(v + 12) = *(const float4*)(zr + f * 64 + 12);
      int dg[16][4];
#pragma unroll
      for (int e = 0; e < 16; ++e) dig4(v[e] * 16.0f, dg[e]);  // |z*16| <= ~92
#pragma unroll
      for (int p = 0; p < 4; ++p) {
        int4v wv;
#pragma unroll
        for (int wi = 0; wi < 4; ++wi)
          wv[wi] = (dg[wi * 4][p] & 255) | ((dg[wi * 4 + 1][p] & 255) << 8) |
                   ((dg[wi * 4 + 2][p] & 255) << 16) | (dg[wi * 4 + 3][p] << 24);
        Adig[p][f] = wv;
      }
    }
  }

  const char* cbd_b = cbd;
  // stage ALL 4 planes (32KB) of code-tile ntv into dstbase (linear, lane-ordered)
#define STAGE_ALL(ntv, dstbase) do { \
    const char* s_ = cbd_b + (size_t)(ntv) * 8192 + tid * 16; \
    char* d_ = (dstbase) + tid * 16; \
    gl_lds16(s_,          d_);          gl_lds16(s_ + 4096,   d_ + 4096); \
    gl_lds16(s_ + 262144, d_ + 8192);   gl_lds16(s_ + 266240, d_ + 12288); \
    gl_lds16(s_ + 524288, d_ + 16384);  gl_lds16(s_ + 528384, d_ + 20480); \
    gl_lds16(s_ + 786432, d_ + 24576);  gl_lds16(s_ + 790528, d_ + 28672); \
  } while (0)

  float bd[4]; int bi[4];
#pragma unroll
  for (int r = 0; r < 4; ++r) { bd[r] = 3.4e38f; bi[r] = 0x7fffffff; }

  int4v acc[4][2];

  STAGE_ALL(0, &bbuf[0][0]);
  __syncthreads();  // stage(0) complete + c2s visible

  for (int nt = 0; nt < NT; ++nt) {
    const char* cur = &bbuf[nt & 1][0];
    if (nt + 1 < NT) STAGE_ALL(nt + 1, &bbuf[(nt + 1) & 1][0]);  // fly during compute
#pragma unroll
    for (int s = 0; s < 4; ++s) {
      int4v zz = {0, 0, 0, 0};
      acc[s][0] = zz; acc[s][1] = zz;
    }
    // all 4 planes resident: 32 ds_reads + 80 MFMAs per wave, no barriers inside
#pragma unroll
    for (int j = 0; j < 4; ++j) {
#pragma unroll
      for (int f = 0; f < 4; ++f) {
        // contiguous 1024B per wave per read: zero bank conflicts
        int4v B0 = *(const int4v*)(cur + j * 8192 + f * 2048 + lane * 16);
        int4v B1 = *(const int4v*)(cur + j * 8192 + f * 2048 + 1024 + lane * 16);
        acc[j + 0][0] = MFI(Adig[0][f], B0, acc[j + 0][0]);
        acc[j + 0][1] = MFI(Adig[0][f], B1, acc[j + 0][1]);
        if (j < 3) { acc[j + 1][0] = MFI(Adig[1][f], B0, acc[j + 1][0]);
                     acc[j + 1][1] = MFI(Adig[1][f], B1, acc[j + 1][1]); }
        if (j < 2) { acc[j + 2][0] = MFI(Adig[2][f], B0, acc[j + 2][0]);
                     acc[j + 2][1] = MFI(Adig[2][f], B1, acc[j + 2][1]); }
        if (j < 1) { acc[j + 3][0] = MFI(Adig[3][f], B0, acc[j + 3][0]);
                     acc[j + 3][1] = MFI(Adig[3][f], B1, acc[j + 3][1]); }
      }
    }
    // finalize: exact int64 recombination of integer group sums, one fp32 rounding
#pragma unroll
    for (int n = 0; n < 2; ++n) {
#pragma unroll
      for (int r = 0; r < 4; ++r) {
        long M = (long)acc[0][n][r];
        M = (M << 8) + acc[1][n][r];
        M = (M << 8) + acc[2][n][r];
        M = (M << 8) + acc[3][n][r];              // = sum_s acc_s * 256^(3-s), exact
        float mf = (float)((double)M * 0x1p-44);  // m rounded once (bit-identical to r2-r5)
        int kc = nt * BN + n * 16 + l15;
        float dist = __fsub_rn(__fadd_rn(sr[r], c2s[kc]), __fmul_rn(2.0f, mf));
        if (dist < bd[r]) { bd[r] = dist; bi[r] = kc; }  // ascending kc => first-min
      }
    }
    __syncthreads();  // one barrier per nt: drains stage(nt+1), fences cur readers
  }

  // per-row argmin across the 16 lanes of each row group (np tie-break: lowest idx)
#pragma unroll
  for (int r = 0; r < 4; ++r) {
#pragma unroll
    for (int m = 1; m < 16; m <<= 1) {
      float od = __shfl_xor(bd[r], m);
      int oi = __shfl_xor(bi[r], m);
      if (od < bd[r] || (od == bd[r] && oi < bi[r])) { bd[r] = od; bi[r] = oi; }
    }
    if (l15 == 0) bidx_s[w * 16 + l4 * 4 + r] = bi[r];
  }
  __syncthreads();

  // epilogue: wave-per-row, lane-contiguous 1KB stores (full 64B lines per instr;
  // round-1 pattern whose WRITE_SIZE == output size exactly)
  {
    float* out0 = out;
    float* out1 = out + (size_t)NROWS * D;
#pragma unroll
    for (int rr = 0; rr < 16; ++rr) {
      const int row_l = w * 16 + rr;
      const int grow = r0 + row_l;
      const int kb = bidx_s[row_l];
      float4 c4 = *(const float4*)(cb + (size_t)kb * D + lane * 4);
      float4 z4 = *(const float4*)(z + (size_t)grow * D + lane * 4);
      float4 q;
      q.x = __fadd_rn(z4.x, __fsub_rn(c4.x, z4.x));
      q.y = __fadd_rn(z4.y, __fsub_rn(c4.y, z4.y));
      q.z = __fadd_rn(z4.z, __fsub_rn(c4.z, z4.z));
      q.w = __fadd_rn(z4.w, __fsub_rn(c4.w, z4.w));
      *(float4*)(out0 + (size_t)grow * D + lane * 4) = q;
      *(float4*)(out1 + (size_t)grow * D + lane * 4) = c4;
    }
  }
}

// ---------------- fallback (exact fp64 dot) if ws is too small ----------------
__global__ void c2_kernel_fb(const float* __restrict__ cb, float* __restrict__ c2) {
  int k = blockIdx.x * blockDim.x + threadIdx.x;
  if (k < KCODES) c2[k] = np_sumsq256(cb + (size_t)k * D);
}

__global__ __launch_bounds__(256) void vq_fallback(const float* __restrict__ z,
                                                   const float* __restrict__ cb,
                                                   const float* __restrict__ c2,
                                                   float* __restrict__ out) {
  __shared__ float zs[64][260];
  __shared__ float cs[64][260];
  __shared__ float srow[64];
  __shared__ int bidx[64];
  const int tid = threadIdx.x;
  const int tx = tid & 15, ty = tid >> 4;
  const int r0 = blockIdx.x * 64;
#pragma unroll
  for (int it = 0; it < 16; ++it) {
    int g = tid + it * 256, row = g >> 6, f4 = g & 63;
    *(float4*)(&zs[row][f4 * 4]) = *(const float4*)(z + (size_t)(r0 + row) * D + f4 * 4);
  }
  __syncthreads();
  if (tid < 64) srow[tid] = np_sumsq256(&zs[tid][0]);
  float bd[4]; int bi[4];
#pragma unroll
  for (int j = 0; j < 4; ++j) { bd[j] = 3.4e38f; bi[j] = 0x7fffffff; }
  for (int t = 0; t < KCODES / 64; ++t) {
    __syncthreads();
#pragma unroll
    for (int it = 0; it < 16; ++it) {
      int g = tid + it * 256, row = g >> 6, f4 = g & 63;
      *(float4*)(&cs[row][f4 * 4]) = *(const float4*)(cb + (size_t)(t * 64 + row) * D + f4 * 4);
    }
    __syncthreads();
    double acc[4][4];
#pragma unroll
    for (int j = 0; j < 4; ++j)
#pragma unroll
      for (int i = 0; i < 4; ++i) acc[j][i] = 0.0;
#pragma unroll 2
    for (int d = 0; d < D; d += 4) {
      float4 a[4], b[4];
#pragma unroll
      for (int j = 0; j < 4; ++j) a[j] = *(const float4*)(&zs[ty + 16 * j][d]);
#pragma unroll
      for (int i = 0; i < 4; ++i) b[i] = *(const float4*)(&cs[tx + 16 * i][d]);
#pragma unroll
      for (int j = 0; j < 4; ++j)
#pragma unroll
        for (int i = 0; i < 4; ++i) {
          acc[j][i] += (double)a[j].x * (double)b[i].x;
          acc[j][i] += (double)a[j].y * (double)b[i].y;
          acc[j][i] += (double)a[j].z * (double)b[i].z;
          acc[j][i] += (double)a[j].w * (double)b[i].w;
        }
    }
#pragma unroll
    for (int j = 0; j < 4; ++j) {
      const float s = srow[ty + 16 * j];
#pragma unroll
      for (int i = 0; i < 4; ++i) {
        const int k = t * 64 + tx + 16 * i;
        const float m = (float)acc[j][i];
        const float dist = __fsub_rn(__fadd_rn(s, c2[k]), __fmul_rn(2.0f, m));
        if (dist < bd[j]) { bd[j] = dist; bi[j] = k; }
      }
    }
  }
  __syncthreads();
  float* red_d = &cs[0][0];
  int* red_i = (int*)&cs[20][0];
#pragma unroll
  for (int j = 0; j < 4; ++j) {
    red_d[(ty + 16 * j) * 16 + tx] = bd[j];
    red_i[(ty + 16 * j) * 16 + tx] = bi[j];
  }
  __syncthreads();
  if (tid < 64) {
    float best = red_d[tid * 16 + 0];
    int bsti = red_i[tid * 16 + 0];
    for (int x = 1; x < 16; ++x) {
      float d2 = red_d[tid * 16 + x]; int i2 = red_i[tid * 16 + x];
      if (d2 < best || (d2 == best && i2 < bsti)) { best = d2; bsti = i2; }
    }
    bidx[tid] = bsti;
  }
  __syncthreads();
  const int wid = tid >> 6, lane = tid & 63;
  float* out0 = out;
  float* out1 = out + (size_t)NROWS * D;
  for (int r = wid; r < 64; r += 4) {
    const int gr = r0 + r;
    const int kb = bidx[r];
    float4 c4 = *(const float4*)(cb + (size_t)kb * D + lane * 4);
    float4 z4 = *(const float4*)(&zs[r][lane * 4]);
    float4 q;
    q.x = __fadd_rn(z4.x, __fsub_rn(c4.x, z4.x));
    q.y = __fadd_rn(z4.y, __fsub_rn(c4.y, z4.y));
    q.z = __fadd_rn(z4.z, __fsub_rn(c4.z, z4.z));
    q.w = __fadd_rn(z4.w, __fsub_rn(c4.w, z4.w));
    *(float4*)(out0 + (size_t)gr * D + lane * 4) = q;
    *(float4*)(out1 + (size_t)gr * D + lane * 4) = c4;
  }
}

extern "C" void kernel_launch(void* const* d_in, const int* in_sizes, int n_in,
                              void* d_out, int out_size, void* d_ws, size_t ws_size,
                              hipStream_t stream) {
  const float* z = (const float*)d_in[0];
  const float* cb = (const float*)d_in[1];
  float* out = (float*)d_out;

  const size_t c2_off = 0;                 // 4 KB
  const size_t srow_off = 4096;            // 256 KB
  const size_t cbd_off = 4096 + 262144;    // 1 MB int8 digit planes
  const size_t need = cbd_off + (size_t)4 * KCODES * 256;

  if (ws_size < need) {  // safety fallback: exact fp64 path
    float* c2 = (float*)d_ws;
    c2_kernel_fb<<<KCODES / 256, 256, 0, stream>>>(cb, c2);
    vq_fallback<<<NROWS / 64, 256, 0, stream>>>(z, cb, c2, out);
    return;
  }

  float* c2 = (float*)((char*)d_ws + c2_off);
  float* srow = (float*)((char*)d_ws + srow_off);
  char* cbd = (char*)d_ws + cbd_off;

  prep_sums<<<(NROWS + KCODES) / 256, 256, 0, stream>>>(z, cb, c2, srow);
  prep_cbdig<<<(KCODES * 16) / 256, 256, 0, stream>>>(cb, cbd);
  vq_mfma<<<NROWS / BM, 256, 0, stream>>>(z, cb, c2, srow, cbd, out);
}

// Round 7
// 207.899 us; speedup vs baseline: 1.7915x; 1.0329x over previous
//
#include <hip/hip_runtime.h>
#include <stdint.h>

#define D 256
#define KCODES 1024
#define NROWS 65536

using int4v  = __attribute__((ext_vector_type(4))) int;
using int16v = __attribute__((ext_vector_type(16))) int;

__device__ __forceinline__ float rne_f(float x) { return __builtin_rintf(x); }

__device__ __forceinline__ void gl_lds16(const void* g, void* l) {
  __builtin_amdgcn_global_load_lds(
      (const __attribute__((address_space(1))) void*)g,
      (__attribute__((address_space(3))) void*)l, 16, 0, 0);
}

// 4 balanced radix-256 digits of t (|t| <= ~92), each in [-128,127] after an
// exact borrow re-encode of the +128 boundary. Value identical to the
// rounds-2..6 digit chain => bit-identical m.
__device__ __forceinline__ void dig4(float t, int* d) {
  float f0 = rne_f(t);  float t1 = __fmul_rn(__fsub_rn(t, f0), 256.0f);
  float f1 = rne_f(t1); float t2 = __fmul_rn(__fsub_rn(t1, f1), 256.0f);
  float f2 = rne_f(t2); float t3 = __fmul_rn(__fsub_rn(t2, f2), 256.0f);
  float f3 = rne_f(t3);
  int d0 = (int)f0, d1 = (int)f1, d2 = (int)f2, d3 = (int)f3;
  if (d3 == 128) { d3 = -128; ++d2; }
  if (d2 == 128) { d2 = -128; ++d1; }
  if (d1 == 128) { d1 = -128; ++d0; }
  d[0] = d0; d[1] = d1; d[2] = d2; d[3] = d3;
}

// ---------- numpy-exact pairwise sum of squares over 256 elements ----------
__device__ __forceinline__ float np_block128_sumsq(const float* __restrict__ q) {
  float r[8], v[8];
  *(float4*)(v) = *(const float4*)(q);
  *(float4*)(v + 4) = *(const float4*)(q + 4);
#pragma unroll
  for (int j = 0; j < 8; ++j) r[j] = __fmul_rn(v[j], v[j]);
  for (int i = 8; i < 128; i += 8) {
    *(float4*)(v) = *(const float4*)(q + i);
    *(float4*)(v + 4) = *(const float4*)(q + i + 4);
#pragma unroll
    for (int j = 0; j < 8; ++j) r[j] = __fadd_rn(r[j], __fmul_rn(v[j], v[j]));
  }
  float t01 = __fadd_rn(r[0], r[1]);
  float t23 = __fadd_rn(r[2], r[3]);
  float t45 = __fadd_rn(r[4], r[5]);
  float t67 = __fadd_rn(r[6], r[7]);
  return __fadd_rn(__fadd_rn(t01, t23), __fadd_rn(t45, t67));
}
__device__ __forceinline__ float np_sumsq256(const float* __restrict__ q) {
  return __fadd_rn(np_block128_sumsq(q), np_block128_sumsq(q + 128));
}

// prep1: srow[65536] and c2[1024], numpy-exact
__global__ void prep_sums(const float* __restrict__ z, const float* __restrict__ cb,
                          float* __restrict__ c2, float* __restrict__ srow) {
  int r = blockIdx.x * blockDim.x + threadIdx.x;
  if (r < NROWS) srow[r] = np_sumsq256(z + (size_t)r * D);
  else if (r < NROWS + KCODES) c2[r - NROWS] = np_sumsq256(cb + (size_t)(r - NROWS) * D);
}

// prep2: codebook -> 4 int8 digit planes, k-major tile layout (unchanged from r5/r6):
// plane j, code-tile nt (32 codes) is an 8KB tile [f(0..3)][c16(0..1)][kgrp(0..3)]
// [code(0..15)][16 i8]; the 16B chunk covers k = f*64 + kgrp*16 .. +16.
__global__ void prep_cbdig(const float* __restrict__ cb, char* __restrict__ cbd) {
  int id = blockIdx.x * blockDim.x + threadIdx.x;  // 16384 threads
  int n = id >> 4, kc = id & 15;
  int f = kc >> 2, kg = kc & 3, nt = n >> 5, c = n & 31;
  const float* src = cb + (size_t)n * D + kc * 16;
  float v[16];
  *(float4*)(v) = *(const float4*)(src);
  *(float4*)(v + 4) = *(const float4*)(src + 4);
  *(float4*)(v + 8) = *(const float4*)(src + 8);
  *(float4*)(v + 12) = *(const float4*)(src + 12);
  int dg[16][4];
#pragma unroll
  for (int e = 0; e < 16; ++e) dig4(v[e] * 65536.0f, dg[e]);  // |c*2^16| <= 64
  size_t base = (size_t)nt * 8192 + f * 2048 + (c >> 4) * 1024 + kg * 256 + (c & 15) * 16;
#pragma unroll
  for (int p = 0; p < 4; ++p) {
    int4v wv;
#pragma unroll
    for (int wi = 0; wi < 4; ++wi)
      wv[wi] = (dg[wi * 4][p] & 255) | ((dg[wi * 4 + 1][p] & 255) << 8) |
               ((dg[wi * 4 + 2][p] & 255) << 16) | (dg[wi * 4 + 3][p] << 24);
    *(int4v*)(cbd + (size_t)p * (KCODES * 256) + base) = wv;
  }
}

// ---------------- main MFMA kernel (int8 32x32x32, exact integer accumulation) ----------------
#define BM 128
#define BN 32
#define NT (KCODES / BN)

#define MFI32(a, b, c) __builtin_amdgcn_mfma_i32_32x32x32_i8((a), (b), (c), 0, 0, 0)

__global__ __launch_bounds__(256, 1) void vq_mfma(
    const float* __restrict__ z, const float* __restrict__ cb,
    const float* __restrict__ c2g, const float* __restrict__ srowg,
    const char* __restrict__ cbd, float* __restrict__ out) {
  // double-buffered: per buffer all 4 planes of one 32-code tile (4 x 8KB)
  __shared__ alignas(16) char bbuf[2][32768];
  __shared__ float c2s[KCODES];
  __shared__ float srow_s[BM];
  __shared__ int bidx_s[BM];

  const int tid = threadIdx.x;
  const int lane = tid & 63;
  const int w = tid >> 6;        // wave 0..3, owns rows w*32..w*32+31
  const int r0 = blockIdx.x * BM;
  const int l31 = lane & 31, hi = lane >> 5;

  c2s[tid] = c2g[tid];
  c2s[tid + 256] = c2g[tid + 256];
  c2s[tid + 512] = c2g[tid + 512];
  c2s[tid + 768] = c2g[tid + 768];
  if (tid < BM) srow_s[tid] = srowg[r0 + tid];

  // ---- A digits: 4 planes x 8 kfrags (32x32x32 A layout: row=l31, k=kf*32+hi*16+e) ----
  int4v Adig[4][8];
  {
    const float* zr = z + (size_t)(r0 + w * 32 + l31) * D + hi * 16;
#pragma unroll
    for (int kf = 0; kf < 8; ++kf) {
      float v[16];
      *(float4*)(v) = *(const float4*)(zr + kf * 32);
      *(float4*)(v + 4) = *(const float4*)(zr + kf * 32 + 4);
      *(float4*)(v + 8) = *(const float4*)(zr + kf * 32 + 8);
      *(float4*)(v + 12) = *(const float4*)(zr + kf * 32 + 12);
      int dg[16][4];
#pragma unroll
      for (int e = 0; e < 16; ++e) dig4(v[e] * 16.0f, dg[e]);  // |z*16| <= ~92
#pragma unroll
      for (int p = 0; p < 4; ++p) {
        int4v wv;
#pragma unroll
        for (int wi = 0; wi < 4; ++wi)
          wv[wi] = (dg[wi * 4][p] & 255) | ((dg[wi * 4 + 1][p] & 255) << 8) |
                   ((dg[wi * 4 + 2][p] & 255) << 16) | (dg[wi * 4 + 3][p] << 24);
        Adig[p][kf] = wv;
      }
    }
  }

  const char* cbd_b = cbd;
#define STAGE_ALL(ntv, dstbase) do { \
    const char* s_ = cbd_b + (size_t)(ntv) * 8192 + tid * 16; \
    char* d_ = (dstbase) + tid * 16; \
    gl_lds16(s_,          d_);          gl_lds16(s_ + 4096,   d_ + 4096); \
    gl_lds16(s_ + 262144, d_ + 8192);   gl_lds16(s_ + 266240, d_ + 12288); \
    gl_lds16(s_ + 524288, d_ + 16384);  gl_lds16(s_ + 528384, d_ + 20480); \
    gl_lds16(s_ + 786432, d_ + 24576);  gl_lds16(s_ + 790528, d_ + 28672); \
  } while (0)

  // per-lane LDS offset for B frags (32x32 B layout: col=l31, k=kf*32+hi*16+e)
  const int laneoff = ((lane >> 4) & 1) * 1024 + hi * 256 + (lane & 15) * 16;

  float bd[16]; int bi[16];
#pragma unroll
  for (int r = 0; r < 16; ++r) { bd[r] = 3.4e38f; bi[r] = 0x7fffffff; }

  int16v acc[4];

  STAGE_ALL(0, &bbuf[0][0]);
  __syncthreads();  // stage(0) complete + c2s/srow_s visible

  for (int nt = 0; nt < NT; ++nt) {
    const char* cur = &bbuf[nt & 1][0];
    if (nt + 1 < NT) STAGE_ALL(nt + 1, &bbuf[(nt + 1) & 1][0]);  // fly during compute
#pragma unroll
    for (int s = 0; s < 4; ++s) {
      int16v zz = {0};
      acc[s] = zz;
    }
    // all 4 planes resident: 32 ds_reads + 80 MFMAs (32x32x32) per wave
#pragma unroll
    for (int j = 0; j < 4; ++j) {
#pragma unroll
      for (int kf = 0; kf < 8; ++kf) {
        int4v B = *(const int4v*)(cur + j * 8192 + (kf >> 1) * 2048 + (kf & 1) * 512 + laneoff);
        acc[j + 0] = MFI32(Adig[0][kf], B, acc[j + 0]);
        if (j < 3) acc[j + 1] = MFI32(Adig[1][kf], B, acc[j + 1]);
        if (j < 2) acc[j + 2] = MFI32(Adig[2][kf], B, acc[j + 2]);
        if (j < 1) acc[j + 3] = MFI32(Adig[3][kf], B, acc[j + 3]);
      }
    }
    // finalize: exact fp64 Horner of the 4 integer group sums (all steps exact,
    // one fp32 rounding => m bit-identical to rounds 2-6)
    {
      const int kc = nt * BN + l31;
      const float c2v = c2s[kc];
#pragma unroll
      for (int r = 0; r < 16; ++r) {
        double md = fma(fma(fma((double)acc[0][r], 256.0, (double)acc[1][r]),
                            256.0, (double)acc[2][r]),
                        256.0, (double)acc[3][r]) * 0x1p-44;
        float mf = (float)md;
        const int row_l = w * 32 + (r & 3) + ((r >> 2) << 3) + (hi << 2);
        float dist = __fsub_rn(__fadd_rn(srow_s[row_l], c2v), __fmul_rn(2.0f, mf));
        if (dist < bd[r]) { bd[r] = dist; bi[r] = kc; }  // ascending kc => first-min
      }
    }
    __syncthreads();  // one barrier per nt: drains stage(nt+1), fences cur readers
  }

  // per-row argmin across the 32 code-lanes of each half (np tie-break: lowest idx)
#pragma unroll
  for (int r = 0; r < 16; ++r) {
#pragma unroll
    for (int m = 1; m < 32; m <<= 1) {
      float od = __shfl_xor(bd[r], m);
      int oi = __shfl_xor(bi[r], m);
      if (od < bd[r] || (od == bd[r] && oi < bi[r])) { bd[r] = od; bi[r] = oi; }
    }
    if (l31 == 0) bidx_s[w * 32 + (r & 3) + ((r >> 2) << 3) + (hi << 2)] = bi[r];
  }
  __syncthreads();

  // epilogue: wave-per-row, lane-contiguous 1KB stores (WRITE_SIZE == output size)
  {
    float* out0 = out;
    float* out1 = out + (size_t)NROWS * D;
#pragma unroll
    for (int rr = 0; rr < 32; ++rr) {
      const int row_l = w * 32 + rr;
      const int grow = r0 + row_l;
      const int kb = bidx_s[row_l];
      float4 c4 = *(const float4*)(cb + (size_t)kb * D + lane * 4);
      float4 z4 = *(const float4*)(z + (size_t)grow * D + lane * 4);
      float4 q;
      q.x = __fadd_rn(z4.x, __fsub_rn(c4.x, z4.x));
      q.y = __fadd_rn(z4.y, __fsub_rn(c4.y, z4.y));
      q.z = __fadd_rn(z4.z, __fsub_rn(c4.z, z4.z));
      q.w = __fadd_rn(z4.w, __fsub_rn(c4.w, z4.w));
      *(float4*)(out0 + (size_t)grow * D + lane * 4) = q;
      *(float4*)(out1 + (size_t)grow * D + lane * 4) = c4;
    }
  }
}

// ---------------- fallback (exact fp64 dot) if ws is too small ----------------
__global__ void c2_kernel_fb(const float* __restrict__ cb, float* __restrict__ c2) {
  int k = blockIdx.x * blockDim.x + threadIdx.x;
  if (k < KCODES) c2[k] = np_sumsq256(cb + (size_t)k * D);
}

__global__ __launch_bounds__(256) void vq_fallback(const float* __restrict__ z,
                                                   const float* __restrict__ cb,
                                                   const float* __restrict__ c2,
                                                   float* __restrict__ out) {
  __shared__ float zs[64][260];
  __shared__ float cs[64][260];
  __shared__ float srow[64];
  __shared__ int bidx[64];
  const int tid = threadIdx.x;
  const int tx = tid & 15, ty = tid >> 4;
  const int r0 = blockIdx.x * 64;
#pragma unroll
  for (int it = 0; it < 16; ++it) {
    int g = tid + it * 256, row = g >> 6, f4 = g & 63;
    *(float4*)(&zs[row][f4 * 4]) = *(const float4*)(z + (size_t)(r0 + row) * D + f4 * 4);
  }
  __syncthreads();
  if (tid < 64) srow[tid] = np_sumsq256(&zs[tid][0]);
  float bd[4]; int bi[4];
#pragma unroll
  for (int j = 0; j < 4; ++j) { bd[j] = 3.4e38f; bi[j] = 0x7fffffff; }
  for (int t = 0; t < KCODES / 64; ++t) {
    __syncthreads();
#pragma unroll
    for (int it = 0; it < 16; ++it) {
      int g = tid + it * 256, row = g >> 6, f4 = g & 63;
      *(float4*)(&cs[row][f4 * 4]) = *(const float4*)(cb + (size_t)(t * 64 + row) * D + f4 * 4);
    }
    __syncthreads();
    double acc[4][4];
#pragma unroll
    for (int j = 0; j < 4; ++j)
#pragma unroll
      for (int i = 0; i < 4; ++i) acc[j][i] = 0.0;
#pragma unroll 2
    for (int d = 0; d < D; d += 4) {
      float4 a[4], b[4];
#pragma unroll
      for (int j = 0; j < 4; ++j) a[j] = *(const float4*)(&zs[ty + 16 * j][d]);
#pragma unroll
      for (int i = 0; i < 4; ++i) b[i] = *(const float4*)(&cs[tx + 16 * i][d]);
#pragma unroll
      for (int j = 0; j < 4; ++j)
#pragma unroll
        for (int i = 0; i < 4; ++i) {
          acc[j][i] += (double)a[j].x * (double)b[i].x;
          acc[j][i] += (double)a[j].y * (double)b[i].y;
          acc[j][i] += (double)a[j].z * (double)b[i].z;
          acc[j][i] += (double)a[j].w * (double)b[i].w;
        }
    }
#pragma unroll
    for (int j = 0; j < 4; ++j) {
      const float s = srow[ty + 16 * j];
#pragma unroll
      for (int i = 0; i < 4; ++i) {
        const int k = t * 64 + tx + 16 * i;
        const float m = (float)acc[j][i];
        const float dist = __fsub_rn(__fadd_rn(s, c2[k]), __fmul_rn(2.0f, m));
        if (dist < bd[j]) { bd[j] = dist; bi[j] = k; }
      }
    }
  }
  __syncthreads();
  float* red_d = &cs[0][0];
  int* red_i = (int*)&cs[20][0];
#pragma unroll
  for (int j = 0; j < 4; ++j) {
    red_d[(ty + 16 * j) * 16 + tx] = bd[j];
    red_i[(ty + 16 * j) * 16 + tx] = bi[j];
  }
  __syncthreads();
  if (tid < 64) {
    float best = red_d[tid * 16 + 0];
    int bsti = red_i[tid * 16 + 0];
    for (int x = 1; x < 16; ++x) {
      float d2 = red_d[tid * 16 + x]; int i2 = red_i[tid * 16 + x];
      if (d2 < best || (d2 == best && i2 < bsti)) { best = d2; bsti = i2; }
    }
    bidx[tid] = bsti;
  }
  __syncthreads();
  const int wid = tid >> 6, lane = tid & 63;
  float* out0 = out;
  float* out1 = out + (size_t)NROWS * D;
  for (int r = wid; r < 64; r += 4) {
    const int gr = r0 + r;
    const int kb = bidx[r];
    float4 c4 = *(const float4*)(cb + (size_t)kb * D + lane * 4);
    float4 z4 = *(const float4*)(&zs[r][lane * 4]);
    float4 q;
    q.x = __fadd_rn(z4.x, __fsub_rn(c4.x, z4.x));
    q.y = __fadd_rn(z4.y, __fsub_rn(c4.y, z4.y));
    q.z = __fadd_rn(z4.z, __fsub_rn(c4.z, z4.z));
    q.w = __fadd_rn(z4.w, __fsub_rn(c4.w, z4.w));
    *(float4*)(out0 + (size_t)gr * D + lane * 4) = q;
    *(float4*)(out1 + (size_t)gr * D + lane * 4) = c4;
  }
}

extern "C" void kernel_launch(void* const* d_in, const int* in_sizes, int n_in,
                              void* d_out, int out_size, void* d_ws, size_t ws_size,
                              hipStream_t stream) {
  const float* z = (const float*)d_in[0];
  const float* cb = (const float*)d_in[1];
  float* out = (float*)d_out;

  const size_t c2_off = 0;                 // 4 KB
  const size_t srow_off = 4096;            // 256 KB
  const size_t cbd_off = 4096 + 262144;    // 1 MB int8 digit planes
  const size_t need = cbd_off + (size_t)4 * KCODES * 256;

  if (ws_size < need) {  // safety fallback: exact fp64 path
    float* c2 = (float*)d_ws;
    c2_kernel_fb<<<KCODES / 256, 256, 0, stream>>>(cb, c2);
    vq_fallback<<<NROWS / 64, 256, 0, stream>>>(z, cb, c2, out);
    return;
  }

  float* c2 = (float*)((char*)d_ws + c2_off);
  float* srow = (float*)((char*)d_ws + srow_off);
  char* cbd = (char*)d_ws + cbd_off;

  prep_sums<<<(NROWS + KCODES) / 256, 256, 0, stream>>>(z, cb, c2, srow);
  prep_cbdig<<<(KCODES * 16) / 256, 256, 0, stream>>>(cb, cbd);
  vq_mfma<<<NROWS / BM, 256, 0, stream>>>(z, cb, c2, srow, cbd, out);
}